// Round 1
// baseline (228.956 us; speedup 1.0000x reference)
//
#include <hip/hip_runtime.h>
#include <math.h>

#define NSH 27
#define CTR 13

// Monotone map f32 -> u32 so unsigned compare == float compare, then pack
// (key, idx) into u64: min over packed = lexicographic (d2 asc, idx asc),
// exactly jax.lax.top_k's tie-break (lower index first).
__device__ __forceinline__ unsigned long long packKey(float d, int idx) {
    unsigned int b = __float_as_uint(d);
    unsigned int key = (b & 0x80000000u) ? ~b : (b | 0x80000000u);
    return ((unsigned long long)key << 32) | (unsigned int)idx;
}

__global__ void __launch_bounds__(256) knn_kernel(
    const float* __restrict__ pos, const float* __restrict__ cell,
    const int* __restrict__ numbers, const int* __restrict__ kptr,
    float* __restrict__ out, int N)
{
    extern __shared__ float d2row[];            // Ns floats
    const int Ns  = NSH * N;
    const int k   = kptr[0];
    const int row = blockIdx.x;
    const int tid = threadIdx.x;
    const int nthr = blockDim.x;

    __shared__ float sh_disp[NSH][3];
    __shared__ float sh_inv[3][3];
    __shared__ float sh_margin[3];
    __shared__ unsigned long long sh_wmin[4];
    __shared__ unsigned long long sh_best;

    if (tid == 0) {
        float c[3][3];
        for (int r = 0; r < 3; ++r)
            for (int d = 0; d < 3; ++d) c[r][d] = cell[r*3+d];
        // row norms, margin (f32, matching jnp order)
        float rn[3];
        for (int r = 0; r < 3; ++r) {
            float s = c[r][0]*c[r][0];
            s += c[r][1]*c[r][1];
            s += c[r][2]*c[r][2];
            rn[r] = sqrtf(s);
        }
        float dx = 0.1f * fminf(rn[0], fminf(rn[1], rn[2]));
        for (int r = 0; r < 3; ++r) sh_margin[r] = dx / rn[r];
        // inv(cell) via double adjugate, rounded to f32
        double a00=c[0][0],a01=c[0][1],a02=c[0][2];
        double a10=c[1][0],a11=c[1][1],a12=c[1][2];
        double a20=c[2][0],a21=c[2][1],a22=c[2][2];
        double det = a00*(a11*a22-a12*a21) - a01*(a10*a22-a12*a20)
                   + a02*(a10*a21-a11*a20);
        double id = 1.0/det;
        sh_inv[0][0]=(float)((a11*a22-a12*a21)*id);
        sh_inv[0][1]=(float)((a02*a21-a01*a22)*id);
        sh_inv[0][2]=(float)((a01*a12-a02*a11)*id);
        sh_inv[1][0]=(float)((a12*a20-a10*a22)*id);
        sh_inv[1][1]=(float)((a00*a22-a02*a20)*id);
        sh_inv[1][2]=(float)((a02*a10-a00*a12)*id);
        sh_inv[2][0]=(float)((a10*a21-a11*a20)*id);
        sh_inv[2][1]=(float)((a01*a20-a00*a21)*id);
        sh_inv[2][2]=(float)((a00*a11-a01*a10)*id);
        // disp[c] = shifts[c] @ cell, shifts in ij meshgrid order
        for (int s = 0; s < NSH; ++s) {
            int ix = s/9 - 1, iy = (s/3)%3 - 1, iz = s%3 - 1;
            for (int d = 0; d < 3; ++d) {
                float v = (float)ix * c[0][d];
                v += (float)iy * c[1][d];
                v += (float)iz * c[2][d];
                sh_disp[s][d] = v;
            }
        }
    }
    __syncthreads();

    const int a_i = row % N;
    const int c_i = row / N;
    const float pix = pos[a_i*3+0] + sh_disp[c_i][0];
    const float piy = pos[a_i*3+1] + sh_disp[c_i][1];
    const float piz = pos[a_i*3+2] + sh_disp[c_i][2];
    float sqi = pix*pix; sqi += piy*piy; sqi += piz*piz;

    bool vi = true;
    for (int d = 0; d < 3; ++d) {
        float f = pix*sh_inv[0][d];
        f += piy*sh_inv[1][d];
        f += piz*sh_inv[2][d];
        float m = sh_margin[d];
        vi = vi && (f >= -m) && (f <= 1.0f + m);
    }

    const long long NsK = (long long)Ns * (long long)k;
    float* oD  = out;
    float* oSA = out +     NsK;
    float* oDA = out + 2LL*NsK;
    float* oSC = out + 3LL*NsK;
    float* oEV = out + 4LL*NsK;
    float* oNS = out + 5LL*NsK;

    if (tid == 0) oNS[row] = (float)numbers[a_i];

    if (!vi) {
        // whole row is BIG: top_k picks indices 0..k-1 in order
        if (tid < k) {
            long long e = (long long)row * k + tid;
            oD[e]  = sqrtf(1e30f);
            oSA[e] = (float)(tid % N);
            oDA[e] = (float)a_i;
            oSC[e] = (float)(tid / N);
            oEV[e] = 0.0f;
        }
        return;
    }

    // fill d2 row into LDS
    {
        int aj = tid % N;
        int cj = tid / N;
        for (int j = tid; j < Ns; j += nthr) {
            float px = pos[aj*3+0] + sh_disp[cj][0];
            float py = pos[aj*3+1] + sh_disp[cj][1];
            float pz = pos[aj*3+2] + sh_disp[cj][2];
            float sqj = px*px; sqj += py*py; sqj += pz*pz;
            bool vj = true;
            for (int d = 0; d < 3; ++d) {
                float f = px*sh_inv[0][d];
                f += py*sh_inv[1][d];
                f += pz*sh_inv[2][d];
                float m = sh_margin[d];
                vj = vj && (f >= -m) && (f <= 1.0f + m);
            }
            float dot = pix*px; dot += piy*py; dot += piz*pz;
            float d2 = (sqi + sqj) - 2.0f*dot;
            d2row[j] = vj ? d2 : 1e30f;
            aj += nthr;
            while (aj >= N) { aj -= N; ++cj; }
        }
    }
    __syncthreads();

    const int lane = tid & 63;
    const int wid  = tid >> 6;
    const int nw   = nthr >> 6;

    for (int s = 0; s < k; ++s) {
        unsigned long long best = 0xFFFFFFFFFFFFFFFFull;
        for (int j = tid; j < Ns; j += nthr) {
            unsigned long long key = packKey(d2row[j], j);
            best = key < best ? key : best;
        }
        for (int off = 32; off > 0; off >>= 1) {
            unsigned long long o = __shfl_down(best, off, 64);
            best = o < best ? o : best;
        }
        if (lane == 0) sh_wmin[wid] = best;
        __syncthreads();
        if (tid == 0) {
            unsigned long long b = sh_wmin[0];
            for (int w = 1; w < nw; ++w) {
                unsigned long long o = sh_wmin[w];
                b = o < b ? o : b;
            }
            sh_best = b;
            int bj = (int)(b & 0xFFFFFFFFull);
            d2row[bj] = INFINITY;   // exclude (distinct-index top_k)
            // unpack d2 and write outputs for this slot
            unsigned int kb = (unsigned int)(b >> 32);
            unsigned int fb = (kb & 0x80000000u) ? (kb & 0x7FFFFFFFu) : ~kb;
            float d2v = __uint_as_float(fb);
            long long e = (long long)row * k + s;
            oD[e]  = sqrtf(fmaxf(d2v, 1e-12f));
            oSA[e] = (float)(bj % N);
            oDA[e] = (float)a_i;
            oSC[e] = (float)(bj / N);
            oEV[e] = (d2v < 1e30f && c_i == CTR) ? 1.0f : 0.0f;
        }
        __syncthreads();
    }
}

extern "C" void kernel_launch(void* const* d_in, const int* in_sizes, int n_in,
                              void* d_out, int out_size, void* d_ws, size_t ws_size,
                              hipStream_t stream) {
    const float* pos     = (const float*)d_in[0];   // [N,3] f32
    const float* cell    = (const float*)d_in[1];   // [3,3] f32
    const int*   numbers = (const int*)d_in[2];     // [N]   i32
    const int*   kptr    = (const int*)d_in[3];     // scalar i32
    float* out = (float*)d_out;

    const int N  = in_sizes[0] / 3;
    const int Ns = NSH * N;
    const size_t shbytes = (size_t)Ns * sizeof(float);

    knn_kernel<<<Ns, 256, shbytes, stream>>>(pos, cell, numbers, kptr, out, N);
}

// Round 2
// 30.739 us; speedup vs baseline: 7.4484x; 7.4484x over previous
//
#include <hip/hip_runtime.h>
#include <math.h>

#define NSH 27
#define CTR 13
#define KFIX 9

// Monotone map f32 -> u32 so unsigned compare == float compare, then pack
// (key, idx) into u64: min over packed = lexicographic (d2 asc, idx asc),
// exactly jax.lax.top_k's tie-break (lower index first).
__device__ __forceinline__ unsigned long long packKey(float d, int idx) {
    unsigned int b = __float_as_uint(d);
    unsigned int key = (b & 0x80000000u) ? ~b : (b | 0x80000000u);
    return ((unsigned long long)key << 32) | (unsigned int)idx;
}

__device__ __forceinline__ void cell_setup(const float* __restrict__ cell,
                                           float (*sh_disp)[3], float (*sh_inv)[3],
                                           float* sh_margin) {
    float c[3][3];
    for (int r = 0; r < 3; ++r)
        for (int d = 0; d < 3; ++d) c[r][d] = cell[r*3+d];
    float rn[3];
    for (int r = 0; r < 3; ++r) {
        float s = c[r][0]*c[r][0];
        s += c[r][1]*c[r][1];
        s += c[r][2]*c[r][2];
        rn[r] = sqrtf(s);
    }
    float dx = 0.1f * fminf(rn[0], fminf(rn[1], rn[2]));
    for (int r = 0; r < 3; ++r) sh_margin[r] = dx / rn[r];
    double a00=c[0][0],a01=c[0][1],a02=c[0][2];
    double a10=c[1][0],a11=c[1][1],a12=c[1][2];
    double a20=c[2][0],a21=c[2][1],a22=c[2][2];
    double det = a00*(a11*a22-a12*a21) - a01*(a10*a22-a12*a20)
               + a02*(a10*a21-a11*a20);
    double id = 1.0/det;
    sh_inv[0][0]=(float)((a11*a22-a12*a21)*id);
    sh_inv[0][1]=(float)((a02*a21-a01*a22)*id);
    sh_inv[0][2]=(float)((a01*a12-a02*a11)*id);
    sh_inv[1][0]=(float)((a12*a20-a10*a22)*id);
    sh_inv[1][1]=(float)((a00*a22-a02*a20)*id);
    sh_inv[1][2]=(float)((a02*a10-a00*a12)*id);
    sh_inv[2][0]=(float)((a10*a21-a11*a20)*id);
    sh_inv[2][1]=(float)((a01*a20-a00*a21)*id);
    sh_inv[2][2]=(float)((a00*a11-a01*a10)*id);
    for (int s = 0; s < NSH; ++s) {
        int ix = s/9 - 1, iy = (s/3)%3 - 1, iz = s%3 - 1;
        for (int d = 0; d < 3; ++d) {
            float v = (float)ix * c[0][d];
            v += (float)iy * c[1][d];
            v += (float)iz * c[2][d];
            sh_disp[s][d] = v;
        }
    }
}

// ---------------- Kernel 1: per-point pos/valid + compaction ----------------
__global__ void __launch_bounds__(256) prep_kernel(
    const float* __restrict__ pos, const float* __restrict__ cell,
    const int* __restrict__ numbers,
    float* __restrict__ out_ns,        // numbers_sc output section
    int* __restrict__ cnt, float4* __restrict__ cand, float4* __restrict__ allPts,
    int N)
{
    __shared__ float sh_disp[NSH][3];
    __shared__ float sh_inv[3][3];
    __shared__ float sh_margin[3];
    if (threadIdx.x == 0) cell_setup(cell, sh_disp, sh_inv, sh_margin);
    __syncthreads();

    const int Ns = NSH * N;
    int j = blockIdx.x * blockDim.x + threadIdx.x;
    if (j >= Ns) return;
    int aj = j % N, cj = j / N;
    float x = pos[aj*3+0] + sh_disp[cj][0];
    float y = pos[aj*3+1] + sh_disp[cj][1];
    float z = pos[aj*3+2] + sh_disp[cj][2];
    bool vj = true;
    for (int d = 0; d < 3; ++d) {
        float f = x*sh_inv[0][d];
        f += y*sh_inv[1][d];
        f += z*sh_inv[2][d];
        float m = sh_margin[d];
        vj = vj && (f >= -m) && (f <= 1.0f + m);
    }
    allPts[j] = make_float4(x, y, z, __int_as_float(vj ? 1 : 0));
    out_ns[j] = (float)numbers[aj];
    if (vj) {
        int p = atomicAdd(cnt, 1);
        cand[p] = make_float4(x, y, z, __int_as_float(j));
    }
}

// ---------------- Kernel 2: one wave per row, register top-9 ----------------
__global__ void __launch_bounds__(256) select_kernel(
    float* __restrict__ out,
    const int* __restrict__ cnt, const float4* __restrict__ cand,
    const float4* __restrict__ allPts, int N, int k)
{
    const int Ns   = NSH * N;
    const int lane = threadIdx.x & 63;
    const int wid  = threadIdx.x >> 6;
    const int row  = blockIdx.x * 4 + wid;
    if (row >= Ns) return;

    const long long NsK = (long long)Ns * (long long)k;
    float* oD  = out;
    float* oSA = out +     NsK;
    float* oDA = out + 2LL*NsK;
    float* oSC = out + 3LL*NsK;
    float* oEV = out + 4LL*NsK;

    const int a_i = row % N;
    const int c_i = row / N;
    float4 me = allPts[row];
    const bool vi = __float_as_int(me.w) != 0;

    if (!vi) {
        if (lane < k) {
            long long e = (long long)row * k + lane;
            oD[e]  = sqrtf(1e30f);
            oSA[e] = (float)(lane % N);
            oDA[e] = (float)a_i;
            oSC[e] = (float)(lane / N);
            oEV[e] = 0.0f;
        }
        return;
    }

    float sqi = me.x*me.x; sqi += me.y*me.y; sqi += me.z*me.z;
    const int M = *cnt;

    const unsigned long long UMAX = 0xFFFFFFFFFFFFFFFFull;
    unsigned long long lst[KFIX];
    #pragma unroll
    for (int i = 0; i < KFIX; ++i) lst[i] = UMAX;

    for (int j = lane; j < M; j += 64) {
        float4 c = cand[j];
        float sqj = c.x*c.x; sqj += c.y*c.y; sqj += c.z*c.z;
        float dot = me.x*c.x; dot += me.y*c.y; dot += me.z*c.z;
        float d2 = (sqi + sqj) - 2.0f*dot;
        unsigned long long key = packKey(d2, __float_as_int(c.w));
        if (key < lst[KFIX-1]) {
            lst[KFIX-1] = key;
            #pragma unroll
            for (int i = KFIX-1; i > 0; --i) {
                unsigned long long a = lst[i-1], b = lst[i];
                lst[i-1] = a < b ? a : b;
                lst[i]   = a < b ? b : a;
            }
        }
    }

    // merge 64 sorted lists: k rounds of wave-wide min over heads
    unsigned long long mine = UMAX;
    for (int s = 0; s < k; ++s) {
        unsigned long long b = lst[0];
        #pragma unroll
        for (int off = 1; off < 64; off <<= 1) {
            unsigned long long o = __shfl_xor(b, off, 64);
            b = o < b ? o : b;
        }
        if (lst[0] == b) {       // unique: idx in low bits
            #pragma unroll
            for (int i = 0; i < KFIX-1; ++i) lst[i] = lst[i+1];
            lst[KFIX-1] = UMAX;
        }
        if (lane == s) mine = b;
    }

    if (lane < k) {
        int bj = (int)(mine & 0xFFFFFFFFull);
        unsigned int kb = (unsigned int)(mine >> 32);
        unsigned int fb = (kb & 0x80000000u) ? (kb & 0x7FFFFFFFu) : ~kb;
        float d2v = __uint_as_float(fb);
        long long e = (long long)row * k + lane;
        oD[e]  = sqrtf(fmaxf(d2v, 1e-12f));
        oSA[e] = (float)(bj % N);
        oDA[e] = (float)a_i;
        oSC[e] = (float)(bj / N);
        oEV[e] = (d2v < 1e30f && c_i == CTR) ? 1.0f : 0.0f;
    }
}

// ---------------- Fallback: round-1 monolithic kernel ----------------
__global__ void __launch_bounds__(256) knn_kernel(
    const float* __restrict__ pos, const float* __restrict__ cell,
    const int* __restrict__ numbers, const int* __restrict__ kptr,
    float* __restrict__ out, int N)
{
    extern __shared__ float d2row[];
    const int Ns  = NSH * N;
    const int k   = kptr[0];
    const int row = blockIdx.x;
    const int tid = threadIdx.x;
    const int nthr = blockDim.x;

    __shared__ float sh_disp[NSH][3];
    __shared__ float sh_inv[3][3];
    __shared__ float sh_margin[3];
    __shared__ unsigned long long sh_wmin[4];

    if (tid == 0) cell_setup(cell, sh_disp, sh_inv, sh_margin);
    __syncthreads();

    const int a_i = row % N;
    const int c_i = row / N;
    const float pix = pos[a_i*3+0] + sh_disp[c_i][0];
    const float piy = pos[a_i*3+1] + sh_disp[c_i][1];
    const float piz = pos[a_i*3+2] + sh_disp[c_i][2];
    float sqi = pix*pix; sqi += piy*piy; sqi += piz*piz;

    bool vi = true;
    for (int d = 0; d < 3; ++d) {
        float f = pix*sh_inv[0][d];
        f += piy*sh_inv[1][d];
        f += piz*sh_inv[2][d];
        float m = sh_margin[d];
        vi = vi && (f >= -m) && (f <= 1.0f + m);
    }

    const long long NsK = (long long)Ns * (long long)k;
    float* oD  = out;
    float* oSA = out +     NsK;
    float* oDA = out + 2LL*NsK;
    float* oSC = out + 3LL*NsK;
    float* oEV = out + 4LL*NsK;
    float* oNS = out + 5LL*NsK;

    if (tid == 0) oNS[row] = (float)numbers[a_i];

    if (!vi) {
        if (tid < k) {
            long long e = (long long)row * k + tid;
            oD[e]  = sqrtf(1e30f);
            oSA[e] = (float)(tid % N);
            oDA[e] = (float)a_i;
            oSC[e] = (float)(tid / N);
            oEV[e] = 0.0f;
        }
        return;
    }

    {
        int aj = tid % N;
        int cj = tid / N;
        for (int j = tid; j < Ns; j += nthr) {
            float px = pos[aj*3+0] + sh_disp[cj][0];
            float py = pos[aj*3+1] + sh_disp[cj][1];
            float pz = pos[aj*3+2] + sh_disp[cj][2];
            float sqj = px*px; sqj += py*py; sqj += pz*pz;
            bool vj = true;
            for (int d = 0; d < 3; ++d) {
                float f = px*sh_inv[0][d];
                f += py*sh_inv[1][d];
                f += pz*sh_inv[2][d];
                float m = sh_margin[d];
                vj = vj && (f >= -m) && (f <= 1.0f + m);
            }
            float dot = pix*px; dot += piy*py; dot += piz*pz;
            float d2 = (sqi + sqj) - 2.0f*dot;
            d2row[j] = vj ? d2 : 1e30f;
            aj += nthr;
            while (aj >= N) { aj -= N; ++cj; }
        }
    }
    __syncthreads();

    const int lane = tid & 63;
    const int wid  = tid >> 6;
    const int nw   = nthr >> 6;

    for (int s = 0; s < k; ++s) {
        unsigned long long best = 0xFFFFFFFFFFFFFFFFull;
        for (int j = tid; j < Ns; j += nthr) {
            unsigned long long key = packKey(d2row[j], j);
            best = key < best ? key : best;
        }
        for (int off = 32; off > 0; off >>= 1) {
            unsigned long long o = __shfl_down(best, off, 64);
            best = o < best ? o : best;
        }
        if (lane == 0) sh_wmin[wid] = best;
        __syncthreads();
        if (tid == 0) {
            unsigned long long b = sh_wmin[0];
            for (int w = 1; w < nw; ++w) {
                unsigned long long o = sh_wmin[w];
                b = o < b ? o : b;
            }
            int bj = (int)(b & 0xFFFFFFFFull);
            d2row[bj] = INFINITY;
            unsigned int kb = (unsigned int)(b >> 32);
            unsigned int fb = (kb & 0x80000000u) ? (kb & 0x7FFFFFFFu) : ~kb;
            float d2v = __uint_as_float(fb);
            long long e = (long long)row * k + s;
            oD[e]  = sqrtf(fmaxf(d2v, 1e-12f));
            oSA[e] = (float)(bj % N);
            oDA[e] = (float)a_i;
            oSC[e] = (float)(bj / N);
            oEV[e] = (d2v < 1e30f && c_i == CTR) ? 1.0f : 0.0f;
        }
        __syncthreads();
    }
}

extern "C" void kernel_launch(void* const* d_in, const int* in_sizes, int n_in,
                              void* d_out, int out_size, void* d_ws, size_t ws_size,
                              hipStream_t stream) {
    const float* pos     = (const float*)d_in[0];   // [N,3] f32
    const float* cell    = (const float*)d_in[1];   // [3,3] f32
    const int*   numbers = (const int*)d_in[2];     // [N]   i32
    const int*   kptr    = (const int*)d_in[3];     // scalar i32
    float* out = (float*)d_out;

    const int N  = in_sizes[0] / 3;
    const int Ns = NSH * N;
    // out layout: 5 sections of [Ns,k] + [Ns]  ->  k derivable on host
    const int k  = (out_size / Ns - 1) / 5;

    const size_t need = 16 + 2ull * (size_t)Ns * sizeof(float4);
    if (k == KFIX && k <= 64 && ws_size >= need) {
        int*    cnt    = (int*)d_ws;
        float4* cand   = (float4*)((char*)d_ws + 16);
        float4* allPts = cand + Ns;
        hipMemsetAsync(d_ws, 0, 16, stream);
        float* out_ns = out + 5LL * (long long)Ns * k;
        prep_kernel<<<(Ns + 255) / 256, 256, 0, stream>>>(
            pos, cell, numbers, out_ns, cnt, cand, allPts, N);
        select_kernel<<<(Ns + 3) / 4, 256, 0, stream>>>(
            out, cnt, cand, allPts, N, k);
    } else {
        const size_t shbytes = (size_t)Ns * sizeof(float);
        knn_kernel<<<Ns, 256, shbytes, stream>>>(pos, cell, numbers, kptr, out, N);
    }
}

// Round 3
// 25.622 us; speedup vs baseline: 8.9358x; 1.1997x over previous
//
#include <hip/hip_runtime.h>
#include <math.h>

#define NSH 27
#define CTR 13
#define KFIX 9

// Monotone map f32 -> u32 so unsigned compare == float compare, then pack
// (key, idx) into u64: min over packed = lexicographic (d2 asc, idx asc),
// exactly jax.lax.top_k's tie-break (lower index first).
__device__ __forceinline__ unsigned long long packKey(float d, int idx) {
    unsigned int b = __float_as_uint(d);
    unsigned int key = (b & 0x80000000u) ? ~b : (b | 0x80000000u);
    return ((unsigned long long)key << 32) | (unsigned int)idx;
}

__device__ __forceinline__ void cell_setup(const float* __restrict__ cell,
                                           float (*sh_disp)[3], float (*sh_inv)[3],
                                           float* sh_margin) {
    float c[3][3];
    for (int r = 0; r < 3; ++r)
        for (int d = 0; d < 3; ++d) c[r][d] = cell[r*3+d];
    float rn[3];
    for (int r = 0; r < 3; ++r) {
        float s = c[r][0]*c[r][0];
        s += c[r][1]*c[r][1];
        s += c[r][2]*c[r][2];
        rn[r] = sqrtf(s);
    }
    float dx = 0.1f * fminf(rn[0], fminf(rn[1], rn[2]));
    for (int r = 0; r < 3; ++r) sh_margin[r] = dx / rn[r];
    double a00=c[0][0],a01=c[0][1],a02=c[0][2];
    double a10=c[1][0],a11=c[1][1],a12=c[1][2];
    double a20=c[2][0],a21=c[2][1],a22=c[2][2];
    double det = a00*(a11*a22-a12*a21) - a01*(a10*a22-a12*a20)
               + a02*(a10*a21-a11*a20);
    double id = 1.0/det;
    sh_inv[0][0]=(float)((a11*a22-a12*a21)*id);
    sh_inv[0][1]=(float)((a02*a21-a01*a22)*id);
    sh_inv[0][2]=(float)((a01*a12-a02*a11)*id);
    sh_inv[1][0]=(float)((a12*a20-a10*a22)*id);
    sh_inv[1][1]=(float)((a00*a22-a02*a20)*id);
    sh_inv[1][2]=(float)((a02*a10-a00*a12)*id);
    sh_inv[2][0]=(float)((a10*a21-a11*a20)*id);
    sh_inv[2][1]=(float)((a01*a20-a00*a21)*id);
    sh_inv[2][2]=(float)((a00*a11-a01*a10)*id);
    for (int s = 0; s < NSH; ++s) {
        int ix = s/9 - 1, iy = (s/3)%3 - 1, iz = s%3 - 1;
        for (int d = 0; d < 3; ++d) {
            float v = (float)ix * c[0][d];
            v += (float)iy * c[1][d];
            v += (float)iz * c[2][d];
            sh_disp[s][d] = v;
        }
    }
}

// ---- Kernel 1: coalesced default fill + per-point prep + compaction ----
// e in [0, Ns*K): write default (invalid-row) pattern in all 5 sections.
// e in [0, Ns):   numbers_sc, validity, compact valid points into cand.
__global__ void __launch_bounds__(256) prep_fill_kernel(
    const float* __restrict__ pos, const float* __restrict__ cell,
    const int* __restrict__ numbers,
    float* __restrict__ out, int* __restrict__ cnt, float4* __restrict__ cand,
    int N)
{
    __shared__ float sh_disp[NSH][3];
    __shared__ float sh_inv[3][3];
    __shared__ float sh_margin[3];
    if (threadIdx.x == 0) cell_setup(cell, sh_disp, sh_inv, sh_margin);
    __syncthreads();

    const int Ns = NSH * N;
    const long long NsK = (long long)Ns * KFIX;
    float* oD  = out;
    float* oSA = out +     NsK;
    float* oDA = out + 2LL*NsK;
    float* oSC = out + 3LL*NsK;
    float* oEV = out + 4LL*NsK;
    float* oNS = out + 5LL*NsK;

    const int e = blockIdx.x * blockDim.x + threadIdx.x;

    if (e < (int)NsK) {
        int row = e / KFIX;
        int s   = e - row * KFIX;
        oD[e]  = sqrtf(1e30f);
        oSA[e] = (float)(s % N);
        oDA[e] = (float)(row % N);
        oSC[e] = (float)(s / N);
        oEV[e] = 0.0f;
    }

    if (e < Ns) {
        int aj = e % N, cj = e / N;
        float x = pos[aj*3+0] + sh_disp[cj][0];
        float y = pos[aj*3+1] + sh_disp[cj][1];
        float z = pos[aj*3+2] + sh_disp[cj][2];
        bool vj = true;
        for (int d = 0; d < 3; ++d) {
            float f = x*sh_inv[0][d];
            f += y*sh_inv[1][d];
            f += z*sh_inv[2][d];
            float m = sh_margin[d];
            vj = vj && (f >= -m) && (f <= 1.0f + m);
        }
        oNS[e] = (float)numbers[aj];
        if (vj) {
            int p = atomicAdd(cnt, 1);
            cand[p] = make_float4(x, y, z, __int_as_float(e));
        }
    }
}

// ---- Kernel 2: one wave per VALID row (from cand), register top-9 ----
__global__ void __launch_bounds__(256) select_kernel(
    float* __restrict__ out,
    const int* __restrict__ cnt, const float4* __restrict__ cand, int N)
{
    const int Ns   = NSH * N;
    const int lane = threadIdx.x & 63;
    const int wid  = threadIdx.x >> 6;
    const int M    = *cnt;
    const int nwaves = gridDim.x * 4;

    const long long NsK = (long long)Ns * KFIX;
    float* oD  = out;
    float* oSA = out +     NsK;
    float* oDA = out + 2LL*NsK;
    float* oSC = out + 3LL*NsK;
    float* oEV = out + 4LL*NsK;

    const unsigned long long UMAX = 0xFFFFFFFFFFFFFFFFull;

    for (int i = blockIdx.x * 4 + wid; i < M; i += nwaves) {
        float4 me = cand[i];               // wave-uniform load
        const int row = __float_as_int(me.w);
        const int a_i = row % N;
        const int c_i = row / N;
        float sqi = me.x*me.x; sqi += me.y*me.y; sqi += me.z*me.z;

        unsigned long long lst[KFIX];
        #pragma unroll
        for (int q = 0; q < KFIX; ++q) lst[q] = UMAX;

        for (int j = lane; j < M; j += 64) {
            float4 c = cand[j];
            float sqj = c.x*c.x; sqj += c.y*c.y; sqj += c.z*c.z;
            float dot = me.x*c.x; dot += me.y*c.y; dot += me.z*c.z;
            float d2 = (sqi + sqj) - 2.0f*dot;
            unsigned long long key = packKey(d2, __float_as_int(c.w));
            if (key < lst[KFIX-1]) {
                lst[KFIX-1] = key;
                #pragma unroll
                for (int q = KFIX-1; q > 0; --q) {
                    unsigned long long a = lst[q-1], b = lst[q];
                    lst[q-1] = a < b ? a : b;
                    lst[q]   = a < b ? b : a;
                }
            }
        }

        // merge 64 sorted lists: k rounds of wave-wide min over heads
        unsigned long long mine = UMAX;
        #pragma unroll
        for (int s = 0; s < KFIX; ++s) {
            unsigned long long b = lst[0];
            #pragma unroll
            for (int off = 1; off < 64; off <<= 1) {
                unsigned long long o = __shfl_xor(b, off, 64);
                b = o < b ? o : b;
            }
            if (lst[0] == b) {             // unique: idx in low bits
                #pragma unroll
                for (int q = 0; q < KFIX-1; ++q) lst[q] = lst[q+1];
                lst[KFIX-1] = UMAX;
            }
            if (lane == s) mine = b;
        }

        if (lane < KFIX) {
            int bj = (int)(mine & 0xFFFFFFFFull);
            unsigned int kb = (unsigned int)(mine >> 32);
            unsigned int fb = (kb & 0x80000000u) ? (kb & 0x7FFFFFFFu) : ~kb;
            float d2v = __uint_as_float(fb);
            long long e = (long long)row * KFIX + lane;
            oD[e]  = sqrtf(fmaxf(d2v, 1e-12f));
            oSA[e] = (float)(bj % N);
            oDA[e] = (float)a_i;
            oSC[e] = (float)(bj / N);
            oEV[e] = (d2v < 1e30f && c_i == CTR) ? 1.0f : 0.0f;
        }
    }
}

// ---------------- Fallback: round-1 monolithic kernel (k != 9) ----------------
__global__ void __launch_bounds__(256) knn_kernel(
    const float* __restrict__ pos, const float* __restrict__ cell,
    const int* __restrict__ numbers, const int* __restrict__ kptr,
    float* __restrict__ out, int N)
{
    extern __shared__ float d2row[];
    const int Ns  = NSH * N;
    const int k   = kptr[0];
    const int row = blockIdx.x;
    const int tid = threadIdx.x;
    const int nthr = blockDim.x;

    __shared__ float sh_disp[NSH][3];
    __shared__ float sh_inv[3][3];
    __shared__ float sh_margin[3];
    __shared__ unsigned long long sh_wmin[4];

    if (tid == 0) cell_setup(cell, sh_disp, sh_inv, sh_margin);
    __syncthreads();

    const int a_i = row % N;
    const int c_i = row / N;
    const float pix = pos[a_i*3+0] + sh_disp[c_i][0];
    const float piy = pos[a_i*3+1] + sh_disp[c_i][1];
    const float piz = pos[a_i*3+2] + sh_disp[c_i][2];
    float sqi = pix*pix; sqi += piy*piy; sqi += piz*piz;

    bool vi = true;
    for (int d = 0; d < 3; ++d) {
        float f = pix*sh_inv[0][d];
        f += piy*sh_inv[1][d];
        f += piz*sh_inv[2][d];
        float m = sh_margin[d];
        vi = vi && (f >= -m) && (f <= 1.0f + m);
    }

    const long long NsK = (long long)Ns * (long long)k;
    float* oD  = out;
    float* oSA = out +     NsK;
    float* oDA = out + 2LL*NsK;
    float* oSC = out + 3LL*NsK;
    float* oEV = out + 4LL*NsK;
    float* oNS = out + 5LL*NsK;

    if (tid == 0) oNS[row] = (float)numbers[a_i];

    if (!vi) {
        if (tid < k) {
            long long e = (long long)row * k + tid;
            oD[e]  = sqrtf(1e30f);
            oSA[e] = (float)(tid % N);
            oDA[e] = (float)a_i;
            oSC[e] = (float)(tid / N);
            oEV[e] = 0.0f;
        }
        return;
    }

    {
        int aj = tid % N;
        int cj = tid / N;
        for (int j = tid; j < Ns; j += nthr) {
            float px = pos[aj*3+0] + sh_disp[cj][0];
            float py = pos[aj*3+1] + sh_disp[cj][1];
            float pz = pos[aj*3+2] + sh_disp[cj][2];
            float sqj = px*px; sqj += py*py; sqj += pz*pz;
            bool vj = true;
            for (int d = 0; d < 3; ++d) {
                float f = px*sh_inv[0][d];
                f += py*sh_inv[1][d];
                f += pz*sh_inv[2][d];
                float m = sh_margin[d];
                vj = vj && (f >= -m) && (f <= 1.0f + m);
            }
            float dot = pix*px; dot += piy*py; dot += piz*pz;
            float d2 = (sqi + sqj) - 2.0f*dot;
            d2row[j] = vj ? d2 : 1e30f;
            aj += nthr;
            while (aj >= N) { aj -= N; ++cj; }
        }
    }
    __syncthreads();

    const int lane = tid & 63;
    const int wid  = tid >> 6;
    const int nw   = nthr >> 6;

    for (int s = 0; s < k; ++s) {
        unsigned long long best = 0xFFFFFFFFFFFFFFFFull;
        for (int j = tid; j < Ns; j += nthr) {
            unsigned long long key = packKey(d2row[j], j);
            best = key < best ? key : best;
        }
        for (int off = 32; off > 0; off >>= 1) {
            unsigned long long o = __shfl_down(best, off, 64);
            best = o < best ? o : best;
        }
        if (lane == 0) sh_wmin[wid] = best;
        __syncthreads();
        if (tid == 0) {
            unsigned long long b = sh_wmin[0];
            for (int w = 1; w < nw; ++w) {
                unsigned long long o = sh_wmin[w];
                b = o < b ? o : b;
            }
            int bj = (int)(b & 0xFFFFFFFFull);
            d2row[bj] = INFINITY;
            unsigned int kb = (unsigned int)(b >> 32);
            unsigned int fb = (kb & 0x80000000u) ? (kb & 0x7FFFFFFFu) : ~kb;
            float d2v = __uint_as_float(fb);
            long long e = (long long)row * k + s;
            oD[e]  = sqrtf(fmaxf(d2v, 1e-12f));
            oSA[e] = (float)(bj % N);
            oDA[e] = (float)a_i;
            oSC[e] = (float)(bj / N);
            oEV[e] = (d2v < 1e30f && c_i == CTR) ? 1.0f : 0.0f;
        }
        __syncthreads();
    }
}

extern "C" void kernel_launch(void* const* d_in, const int* in_sizes, int n_in,
                              void* d_out, int out_size, void* d_ws, size_t ws_size,
                              hipStream_t stream) {
    const float* pos     = (const float*)d_in[0];   // [N,3] f32
    const float* cell    = (const float*)d_in[1];   // [3,3] f32
    const int*   numbers = (const int*)d_in[2];     // [N]   i32
    const int*   kptr    = (const int*)d_in[3];     // scalar i32
    float* out = (float*)d_out;

    const int N  = in_sizes[0] / 3;
    const int Ns = NSH * N;
    // out layout: 5 sections of [Ns,k] + [Ns]  ->  k derivable on host
    const int k  = (out_size / Ns - 1) / 5;

    const size_t need = 16 + (size_t)Ns * sizeof(float4);
    if (k == KFIX && ws_size >= need) {
        int*    cnt  = (int*)d_ws;
        float4* cand = (float4*)((char*)d_ws + 16);
        hipMemsetAsync(d_ws, 0, 16, stream);
        const int totalE = Ns * KFIX;
        prep_fill_kernel<<<(totalE + 255) / 256, 256, 0, stream>>>(
            pos, cell, numbers, out, cnt, cand, N);
        select_kernel<<<512, 256, 0, stream>>>(out, cnt, cand, N);
    } else {
        const size_t shbytes = (size_t)Ns * sizeof(float);
        knn_kernel<<<Ns, 256, shbytes, stream>>>(pos, cell, numbers, kptr, out, N);
    }
}